// Round 4
// baseline (104.612 us; speedup 1.0000x reference)
//
#include <hip/hip_runtime.h>
#include <hip/hip_fp16.h>

#define NG 64
#define NVOX (NG*NG*NG)
#define NC 16
#define NHID 32
#define NL 10

typedef _Float16 half8 __attribute__((ext_vector_type(8)));
typedef __fp16   fp16x2 __attribute__((ext_vector_type(2)));
typedef float f32x16 __attribute__((ext_vector_type(16)));

union U32H2 { unsigned u; fp16x2 h; __half2 hh; };
union U4H8  { uint4 u; half8 v; };

__device__ __forceinline__ unsigned pkrtz(float a, float b) {
    U32H2 t; t.h = __builtin_amdgcn_cvt_pkrtz(a, b); return t.u;
}
__device__ __forceinline__ f32x16 MF(half8 a, half8 b, f32x16 c) {
    return __builtin_amdgcn_mfma_f32_32x32x16_f16(a, b, c, 0, 0, 0);
}
__device__ __forceinline__ unsigned hfma2u(unsigned a, unsigned b, unsigned c) {
    U32H2 A, B, C, R; A.u = a; B.u = b; C.u = c;
    R.hh = __hfma2(A.hh, B.hh, C.hh); return R.u;
}
// v_permlane32_swap_b32 a,b : a <- [a_lo | b_lo], b <- [a_hi | b_hi]
#define PSWAP(a, b) asm volatile("v_permlane32_swap_b32 %0, %1" : "+v"(a), "+v"(b))

// ---- workspace layout ----
#define GRID_BYTES ((size_t)NVOX * NC * 2)          // 8 MiB f16 voxel-major grid
#define A0F_OFF  GRID_BYTES                          // [5][64] uint4  (half8 A-frags, layer0)
#define AHF_OFF  (A0F_OFF + (size_t)5 * 64 * 16)     // [6][64] uint4  (hidden A-frags)
#define CBF_OFF  (AHF_OFF + (size_t)6 * 64 * 16)     // [12][64] float4 (bias C-frags)
#define WFF_OFF  (CBF_OFF + (size_t)12 * 64 * 16)    // [4][64] float4  (Wf frags)
#define WS_NEED  (WFF_OFF + (size_t)4 * 64 * 16)

// Pre-pack per-lane MFMA weight fragments (same construction R3 did per-wave).
// x k-layout: k0,1=cx,cy k2=cz k3=1(bias) k4..63=PE k64..79=feats.
__device__ void pack_weights_lane(int lane,
    const float* __restrict__ W0, const float* __restrict__ b0,
    const float* __restrict__ Wh, const float* __restrict__ bh,
    const float* __restrict__ Wf,
    uint4* a0f, uint4* ahf, float4* cbf, float4* wff)
{
    const int H = lane >> 5, nn = lane & 31;
#pragma unroll
    for (int s = 0; s < 5; ++s) {
        float e[8];
#pragma unroll
        for (int i = 0; i < 8; ++i) {
            const int k0 = s * 16 + i;
            const float* q0 = (k0 == 3) ? (b0 + nn)
                             : (W0 + (k0 - (k0 >= 4 ? 1 : 0)) * NHID + nn);
            const float* q1 = W0 + (k0 + 8 - 1) * NHID + nn;   // k1>=8, never bias
            e[i] = *(H ? q1 : q0);
        }
        a0f[s * 64 + lane] = make_uint4(pkrtz(e[0], e[1]), pkrtz(e[2], e[3]),
                                        pkrtz(e[4], e[5]), pkrtz(e[6], e[7]));
    }
#pragma unroll
    for (int L = 0; L < 3; ++L) {
#pragma unroll
        for (int t = 0; t < 2; ++t) {
            float e[8];
#pragma unroll
            for (int i = 0; i < 8; ++i)
                e[i] = Wh[(L * NHID + t * 16 + H * 8 + i) * NHID + nn];
            ahf[(L * 2 + t) * 64 + lane] =
                make_uint4(pkrtz(e[0], e[1]), pkrtz(e[2], e[3]),
                           pkrtz(e[4], e[5]), pkrtz(e[6], e[7]));
        }
        float c[16];
#pragma unroll
        for (int r = 0; r < 16; ++r) {
            int nr = (r & 3) + 8 * (r >> 2) + 4 * H;
            c[r] = bh[L * NHID + nr];
        }
#pragma unroll
        for (int q = 0; q < 4; ++q)
            cbf[(L * 4 + q) * 64 + lane] =
                make_float4(c[4 * q], c[4 * q + 1], c[4 * q + 2], c[4 * q + 3]);
    }
    float w[16];
#pragma unroll
    for (int r = 0; r < 16; ++r) {
        int nr = (r & 3) + 8 * (r >> 2) + 4 * H;
        w[r] = Wf[nr];
    }
#pragma unroll
    for (int q = 0; q < 4; ++q)
        wff[q * 64 + lane] = make_float4(w[4 * q], w[4 * q + 1], w[4 * q + 2], w[4 * q + 3]);
}

// ---- pass 1: grid (C,D,H,W) f32 -> voxel-major f16; block 0 also packs weights ----
__global__ __launch_bounds__(256) void prep_kernel(
    const float* __restrict__ in, unsigned* __restrict__ gridh,
    const float* __restrict__ W0, const float* __restrict__ b0,
    const float* __restrict__ Wh, const float* __restrict__ bh,
    const float* __restrict__ Wf,
    uint4* a0f, uint4* ahf, float4* cbf, float4* wff)
{
    int v = blockIdx.x * 256 + threadIdx.x;
    if (v < NVOX) {
        unsigned o[8];
#pragma unroll
        for (int c = 0; c < 8; ++c) {
            float a = in[(2 * c) * NVOX + v];
            float b = in[(2 * c + 1) * NVOX + v];
            U32H2 t; t.hh = __floats2half2_rn(a, b); o[c] = t.u;
        }
        uint4* dst = reinterpret_cast<uint4*>(gridh + (size_t)v * 8);
        dst[0] = make_uint4(o[0], o[1], o[2], o[3]);
        dst[1] = make_uint4(o[4], o[5], o[6], o[7]);
    }
    if (blockIdx.x == 0 && threadIdx.x < 64)
        pack_weights_lane(threadIdx.x, W0, b0, Wh, bh, Wf, a0f, ahf, cbf, wff);
}

// ---- pass 2: fused grid-sample + PE + 4-layer MLP, f16 MFMA ----
// Wave = 64 pts = 2 m-tiles. Layer0 B built via 2-slice double-buffered LDS,
// col-major [col][8 rows] -> b128 writes/reads. Hidden layers register-only.
__global__ __launch_bounds__(256) void fgm_mfma(
    const float* __restrict__ coords, const unsigned* __restrict__ gridh,
    const uint4* __restrict__ a0f, const uint4* __restrict__ ahf,
    const float4* __restrict__ cbf, const float4* __restrict__ wff,
    const float* __restrict__ bf,
    float* __restrict__ out, int n)
{
    __shared__ unsigned lds[4][2][64 * 8];     // 16 KiB/block
    const int lane = threadIdx.x & 63;
    const int wid  = threadIdx.x >> 6;
    const int base = blockIdx.x * 256 + wid * 64;
    if (base >= n) return;
    const int p  = base + lane;
    const int pc = min(p, n - 1);
    const int H  = lane >> 5;
    const int m  = lane & 31;

    float cx = coords[3 * pc + 0], cy = coords[3 * pc + 1], cz = coords[3 * pc + 2];

    // ---- trilinear grid sample, packed f16 ----
    float fx = (cx + 1.0f) * (NG * 0.5f) - 0.5f;
    float fy = (cy + 1.0f) * (NG * 0.5f) - 0.5f;
    float fz = (cz + 1.0f) * (NG * 0.5f) - 0.5f;
    float flx = floorf(fx), fly = floorf(fy), flz = floorf(fz);
    float wx = fx - flx, wy = fy - fly, wz = fz - flz;
    int ix0 = (int)flx, iy0 = (int)fly, iz0 = (int)flz;
    float wxs[2] = {1.0f - wx, wx}, wys[2] = {1.0f - wy, wy}, wzs[2] = {1.0f - wz, wz};

    unsigned fvp[8];
#pragma unroll
    for (int j = 0; j < 8; ++j) fvp[j] = 0u;

#pragma unroll
    for (int dz = 0; dz < 2; ++dz) {
        int zi = iz0 + dz; bool vz = (zi >= 0) && (zi < NG);
        int zc = min(max(zi, 0), NG - 1);
#pragma unroll
        for (int dy = 0; dy < 2; ++dy) {
            int yi = iy0 + dy; bool vy = (yi >= 0) && (yi < NG);
            int yc = min(max(yi, 0), NG - 1);
#pragma unroll
            for (int dx = 0; dx < 2; ++dx) {
                int xi = ix0 + dx; bool vx = (xi >= 0) && (xi < NG);
                int xc = min(max(xi, 0), NG - 1);
                float w = wzs[dz] * wys[dy] * wxs[dx];
                w = (vx && vy && vz) ? w : 0.0f;
                U32H2 w2; w2.hh = __float2half2_rn(w);
                const uint4* g = reinterpret_cast<const uint4*>(
                    gridh + (size_t)(((zc * NG) + yc) * NG + xc) * 8);
                uint4 qa = g[0], qb = g[1];
                fvp[0] = hfma2u(qa.x, w2.u, fvp[0]);
                fvp[1] = hfma2u(qa.y, w2.u, fvp[1]);
                fvp[2] = hfma2u(qa.z, w2.u, fvp[2]);
                fvp[3] = hfma2u(qa.w, w2.u, fvp[3]);
                fvp[4] = hfma2u(qb.x, w2.u, fvp[4]);
                fvp[5] = hfma2u(qb.y, w2.u, fvp[5]);
                fvp[6] = hfma2u(qb.z, w2.u, fvp[6]);
                fvp[7] = hfma2u(qb.w, w2.u, fvp[7]);
            }
        }
    }

    // ---- x pairs in registers (40 u32) ----
    unsigned xr[40];
    xr[0] = pkrtz(cx, cy);
    xr[1] = pkrtz(cz, 1.0f);
#pragma unroll
    for (int l0 = 0; l0 < NL; ++l0) {
        float f = (float)(1 << l0);
        float sx, cax, sy, cay, sz, caz;
        __sincosf(cx * f, &sx, &cax);
        __sincosf(cy * f, &sy, &cay);
        __sincosf(cz * f, &sz, &caz);
        xr[2 + 3 * l0 + 0] = pkrtz(sx, sy);
        xr[2 + 3 * l0 + 1] = pkrtz(sz, cax);
        xr[2 + 3 * l0 + 2] = pkrtz(cay, caz);
    }
#pragma unroll
    for (int j = 0; j < 8; ++j) xr[32 + j] = fvp[j];

    // ---- layer 0: 5 K-slices, double-buffered col-major LDS ----
    f32x16 acc0, acc1;
#pragma unroll
    for (int r = 0; r < 16; ++r) { acc0[r] = 0.0f; acc1[r] = 0.0f; }

    auto wrslice = [&](int s) {
        unsigned* bp = &lds[wid][s & 1][lane * 8];
        reinterpret_cast<uint4*>(bp)[0] =
            make_uint4(xr[8 * s + 0], xr[8 * s + 1], xr[8 * s + 2], xr[8 * s + 3]);
        reinterpret_cast<uint4*>(bp)[1] =
            make_uint4(xr[8 * s + 4], xr[8 * s + 5], xr[8 * s + 6], xr[8 * s + 7]);
    };

    wrslice(0);
#pragma unroll
    for (int s = 0; s < 5; ++s) {
        if (s < 4) wrslice(s + 1);
        const unsigned* rp = &lds[wid][s & 1][m * 8 + H * 4];
        U4H8 b0v, b1v, af;
        b0v.u = *reinterpret_cast<const uint4*>(rp);
        b1v.u = *reinterpret_cast<const uint4*>(rp + 32 * 8);
        af.u  = a0f[s * 64 + lane];
        acc0 = MF(af.v, b0v.v, acc0);
        acc1 = MF(af.v, b1v.v, acc1);
    }

    // ---- hidden layers: snake -> f16 pairs -> permlane B-frags -> MFMA ----
#pragma unroll
    for (int L = 0; L < 3; ++L) {
        unsigned w0a[8], w1a[8];
#pragma unroll
        for (int j = 0; j < 8; ++j) {
            {
                float x0 = acc0[2 * j], x1 = acc0[2 * j + 1];
                float s0 = __sinf(x0), s1 = __sinf(x1);
                w0a[j] = pkrtz(fmaf(0.5f, x0, s0 * s0), fmaf(0.5f, x1, s1 * s1));
            }
            {
                float x0 = acc1[2 * j], x1 = acc1[2 * j + 1];
                float s0 = __sinf(x0), s1 = __sinf(x1);
                w1a[j] = pkrtz(fmaf(0.5f, x0, s0 * s0), fmaf(0.5f, x1, s1 * s1));
            }
        }
        PSWAP(w0a[0], w0a[2]); PSWAP(w0a[1], w0a[3]);
        PSWAP(w0a[4], w0a[6]); PSWAP(w0a[5], w0a[7]);
        PSWAP(w1a[0], w1a[2]); PSWAP(w1a[1], w1a[3]);
        PSWAP(w1a[4], w1a[6]); PSWAP(w1a[5], w1a[7]);

        float4 c0 = cbf[(L * 4 + 0) * 64 + lane];
        float4 c1 = cbf[(L * 4 + 1) * 64 + lane];
        float4 c2 = cbf[(L * 4 + 2) * 64 + lane];
        float4 c3 = cbf[(L * 4 + 3) * 64 + lane];
        f32x16 cb;
        cb[0] = c0.x; cb[1] = c0.y; cb[2]  = c0.z; cb[3]  = c0.w;
        cb[4] = c1.x; cb[5] = c1.y; cb[6]  = c1.z; cb[7]  = c1.w;
        cb[8] = c2.x; cb[9] = c2.y; cb[10] = c2.z; cb[11] = c2.w;
        cb[12] = c3.x; cb[13] = c3.y; cb[14] = c3.z; cb[15] = c3.w;

        U4H8 A0, A1;
        A0.u = ahf[(L * 2 + 0) * 64 + lane];
        A1.u = ahf[(L * 2 + 1) * 64 + lane];

        U4H8 lo0, hi0, lo1, hi1;
        lo0.u = make_uint4(w0a[0], w0a[1], w0a[2], w0a[3]);
        hi0.u = make_uint4(w0a[4], w0a[5], w0a[6], w0a[7]);
        lo1.u = make_uint4(w1a[0], w1a[1], w1a[2], w1a[3]);
        hi1.u = make_uint4(w1a[4], w1a[5], w1a[6], w1a[7]);

        acc0 = MF(A1.v, hi0.v, MF(A0.v, lo0.v, cb));
        acc1 = MF(A1.v, hi1.v, MF(A0.v, lo1.v, cb));
    }

    // ---- final layer: snake -> dot(Wf) -> cross-half reduce ----
    float4 w0v = wff[0 * 64 + lane], w1v = wff[1 * 64 + lane];
    float4 w2v = wff[2 * 64 + lane], w3v = wff[3 * 64 + lane];
    float wfv[16] = {w0v.x, w0v.y, w0v.z, w0v.w, w1v.x, w1v.y, w1v.z, w1v.w,
                     w2v.x, w2v.y, w2v.z, w2v.w, w3v.x, w3v.y, w3v.z, w3v.w};
    float t0 = 0.0f, t1 = 0.0f;
#pragma unroll
    for (int r = 0; r < 16; ++r) {
        float wf = wfv[r];
        { float x = acc0[r]; float s = __sinf(x); t0 = fmaf(fmaf(0.5f, x, s * s), wf, t0); }
        { float x = acc1[r]; float s = __sinf(x); t1 = fmaf(fmaf(0.5f, x, s * s), wf, t1); }
    }
    t0 += __shfl_xor(t0, 32);
    t1 += __shfl_xor(t1, 32);
    float res = (H ? t1 : t0) + bf[0];
    if (p < n) out[p] = res;
}

// ---- fallback (ws too small): scalar fp32 path ----
__global__ __launch_bounds__(256) void fgm_scalar(
    const float* __restrict__ coords, const float* __restrict__ grid,
    const float* __restrict__ W0, const float* __restrict__ b0,
    const float* __restrict__ Wh, const float* __restrict__ bh,
    const float* __restrict__ Wf, const float* __restrict__ bf,
    float* __restrict__ out, int n)
{
    int i = blockIdx.x * blockDim.x + threadIdx.x;
    if (i >= n) return;
    float cx = coords[3 * i + 0], cy = coords[3 * i + 1], cz = coords[3 * i + 2];
    float fx = (cx + 1.0f) * (NG * 0.5f) - 0.5f;
    float fy = (cy + 1.0f) * (NG * 0.5f) - 0.5f;
    float fz = (cz + 1.0f) * (NG * 0.5f) - 0.5f;
    float flx = floorf(fx), fly = floorf(fy), flz = floorf(fz);
    float wx = fx - flx, wy = fy - fly, wz = fz - flz;
    int ix0 = (int)flx, iy0 = (int)fly, iz0 = (int)flz;
    float fv[NC];
#pragma unroll
    for (int c = 0; c < NC; ++c) fv[c] = 0.0f;
    float wxs[2] = {1.0f - wx, wx}, wys[2] = {1.0f - wy, wy}, wzs[2] = {1.0f - wz, wz};
#pragma unroll
    for (int dz = 0; dz < 2; ++dz) {
        int zi = iz0 + dz; bool vz = (zi >= 0) && (zi < NG);
        int zc = min(max(zi, 0), NG - 1);
#pragma unroll
        for (int dy = 0; dy < 2; ++dy) {
            int yi = iy0 + dy; bool vy = (yi >= 0) && (yi < NG);
            int yc = min(max(yi, 0), NG - 1);
#pragma unroll
            for (int dx = 0; dx < 2; ++dx) {
                int xi = ix0 + dx; bool vx = (xi >= 0) && (xi < NG);
                int xc = min(max(xi, 0), NG - 1);
                float w = wzs[dz] * wys[dy] * wxs[dx];
                w = (vx && vy && vz) ? w : 0.0f;
                int off = ((zc * NG) + yc) * NG + xc;
#pragma unroll
                for (int c = 0; c < NC; ++c)
                    fv[c] = fmaf(w, grid[c * NVOX + off], fv[c]);
            }
        }
    }
    float h[NHID];
#pragma unroll
    for (int j = 0; j < NHID; ++j) h[j] = b0[j];
#pragma unroll
    for (int j = 0; j < NHID; ++j) h[j] = fmaf(cx, W0[0 * NHID + j], h[j]);
#pragma unroll
    for (int j = 0; j < NHID; ++j) h[j] = fmaf(cy, W0[1 * NHID + j], h[j]);
#pragma unroll
    for (int j = 0; j < NHID; ++j) h[j] = fmaf(cz, W0[2 * NHID + j], h[j]);
#pragma unroll
    for (int l = 0; l < NL; ++l) {
        float fs = (float)(1 << l);
        float sv[6];
        sv[0] = __sinf(cx * fs); sv[1] = __sinf(cy * fs); sv[2] = __sinf(cz * fs);
        sv[3] = __cosf(cx * fs); sv[4] = __cosf(cy * fs); sv[5] = __cosf(cz * fs);
#pragma unroll
        for (int r = 0; r < 6; ++r) {
            const float* wr = W0 + (size_t)(3 + 6 * l + r) * NHID;
            float a = sv[r];
#pragma unroll
            for (int j = 0; j < NHID; ++j) h[j] = fmaf(a, wr[j], h[j]);
        }
    }
#pragma unroll
    for (int r = 0; r < NC; ++r) {
        const float* wr = W0 + (size_t)(3 + 6 * NL + r) * NHID;
        float a = fv[r];
#pragma unroll
        for (int j = 0; j < NHID; ++j) h[j] = fmaf(a, wr[j], h[j]);
    }
    float act[NHID];
#pragma unroll
    for (int layer = 0; layer < 3; ++layer) {
#pragma unroll
        for (int j = 0; j < NHID; ++j) {
            float s = __sinf(h[j]);
            act[j] = fmaf(0.5f, h[j], s * s);
        }
#pragma unroll
        for (int j = 0; j < NHID; ++j) h[j] = bh[layer * NHID + j];
#pragma unroll
        for (int r = 0; r < NHID; ++r) {
            const float* wr = Wh + (size_t)(layer * NHID + r) * NHID;
            float a = act[r];
#pragma unroll
            for (int j = 0; j < NHID; ++j) h[j] = fmaf(a, wr[j], h[j]);
        }
    }
    float acc = bf[0];
#pragma unroll
    for (int j = 0; j < NHID; ++j) {
        float s = __sinf(h[j]);
        acc = fmaf(fmaf(0.5f, h[j], s * s), Wf[j], acc);
    }
    out[i] = acc;
}

extern "C" void kernel_launch(void* const* d_in, const int* in_sizes, int n_in,
                              void* d_out, int out_size, void* d_ws, size_t ws_size,
                              hipStream_t stream)
{
    const float* coords = (const float*)d_in[0];
    const float* grid   = (const float*)d_in[1];
    const float* W0     = (const float*)d_in[2];
    const float* b0     = (const float*)d_in[3];
    const float* Wh     = (const float*)d_in[4];
    const float* bh     = (const float*)d_in[5];
    const float* Wf     = (const float*)d_in[6];
    const float* bf     = (const float*)d_in[7];
    float* out = (float*)d_out;
    int n = in_sizes[0] / 3;

    if (ws_size >= WS_NEED) {
        char* ws = (char*)d_ws;
        unsigned* gh = (unsigned*)ws;
        uint4*  a0f = (uint4*)(ws + A0F_OFF);
        uint4*  ahf = (uint4*)(ws + AHF_OFF);
        float4* cbf = (float4*)(ws + CBF_OFF);
        float4* wff = (float4*)(ws + WFF_OFF);
        prep_kernel<<<(NVOX + 255) / 256, 256, 0, stream>>>(
            grid, gh, W0, b0, Wh, bh, Wf, a0f, ahf, cbf, wff);
        fgm_mfma<<<(n + 255) / 256, 256, 0, stream>>>(
            coords, gh, a0f, ahf, cbf, wff, bf, out, n);
    } else {
        fgm_scalar<<<(n + 255) / 256, 256, 0, stream>>>(
            coords, grid, W0, b0, Wh, bh, Wf, bf, out, n);
    }
}